// Round 2
// baseline (1242.895 us; speedup 1.0000x reference)
//
#include <hip/hip_runtime.h>

typedef unsigned long long u64;

#define THR 0.5f

// Convert one cxcywh box to ltrb + area, with FP contraction OFF so every op
// matches numpy's rn-per-op semantics bit-exactly (needed for the NMS >= 0.5
// predicate; a fused cx - 0.5*w -> fma differs in the last ulp).
__device__ __forceinline__ void conv_box(const float4 b, float& l, float& t,
                                         float& r, float& bo, float& a) {
  #pragma clang fp contract(off)
  float hw = 0.5f * b.z;
  float hh = 0.5f * b.w;
  l = b.x - hw;
  t = b.y - hh;
  r = b.x + hw;
  bo = b.y + hh;
  a = (r - l) * (bo - t);
}

__global__ void k_zero(int* __restrict__ rank, int n) {
  int i = blockIdx.x * blockDim.x + threadIdx.x;
  if (i < n) rank[i] = 0;
}

// Stable descending rank == stable argsort(-scores) position.
__global__ void k_rank(const float* __restrict__ scores, int* __restrict__ rank,
                       int n, int jchunk) {
  int i = blockIdx.x * blockDim.x + threadIdx.x;
  if (i >= n) return;
  float si = scores[i];
  int j0 = blockIdx.y * jchunk;
  int j1 = min(j0 + jchunk, n);
  int c = 0;
  for (int j = j0; j < j1; ++j) {
    float sj = scores[j];
    c += ((sj > si) || (sj == si && j < i)) ? 1 : 0;
  }
  if (c) atomicAdd(rank + i, c);
}

__global__ void k_scatter(const float4* __restrict__ boxes, const int* __restrict__ rank,
                          float* __restrict__ sl, float* __restrict__ st,
                          float* __restrict__ sr, float* __restrict__ sb,
                          float* __restrict__ sa, int* __restrict__ sidx, int n) {
  int i = blockIdx.x * blockDim.x + threadIdx.x;
  if (i >= n) return;
  float l, t, r, b, a;
  conv_box(boxes[i], l, t, r, b, a);
  int k = rank[i];
  sl[k] = l; st[k] = t; sr[k] = r; sb[k] = b; sa[k] = a; sidx[k] = i;
}

// mask[k][w] bit b (j = w*64+b) set iff j>k, j<n, iou_nms(k,j) >= 0.5.
// Reference does NOT clamp the intersection on the NMS path — replicate
// exactly (contraction off, strict IEEE f32 division, same op order).
__global__ void k_mask(const float* __restrict__ sl, const float* __restrict__ st,
                       const float* __restrict__ sr, const float* __restrict__ sb,
                       const float* __restrict__ sa,
                       u64* __restrict__ mask, u64* __restrict__ diag,
                       int n, int wstride) {
  #pragma clang fp contract(off)
  int k = blockIdx.x * blockDim.x + threadIdx.x;
  if (k >= n) return;
  int w = blockIdx.y;
  int jbase = w << 6;
  u64 word = 0;
  if (jbase + 63 > k) {
    float l = sl[k], t = st[k], r = sr[k], b = sb[k], a = sa[k];
    int jend = min(jbase + 64, n);
    for (int j = max(jbase, k + 1); j < jend; ++j) {
      float lmax = fmaxf(l, sl[j]);
      float tmax = fmaxf(t, st[j]);
      float rmin = fminf(r, sr[j]);
      float bmin = fminf(b, sb[j]);
      float wd = rmin - lmax;
      float hd = bmin - tmax;
      float inter = wd * hd;               // no clamp (matches reference NMS path)
      float denom = (a + sa[j]) - inter;
      float q = inter / denom;             // IEEE f32 div
      if (q >= THR) word |= 1ull << (j - jbase);
    }
  }
  mask[(size_t)k * wstride + w] = word;
  if ((k >> 6) == w) diag[k] = word;
}

// Greedy serial NMS scan — ONE wave. Diagonal 64x64 block staged in LDS
// (dsh), serial chain walks it in 8-word chunks so only 16 VGPRs of chunk
// state are live (round-1 bug: u64 d[64] was demoted to scratch, 846us).
// Single-wave LDS ordering is handled by lgkmcnt — no __syncthreads needed.
__device__ __forceinline__ void scan_body(const u64* __restrict__ mask,
                                          const u64* __restrict__ diag,
                                          const int* __restrict__ sidx,
                                          float* __restrict__ keep,
                                          int n, int wstride,
                                          u64* rem, u64* dsh) {
  int lane = threadIdx.x;
  rem[lane] = 0; rem[lane + 64] = 0; rem[lane + 128] = 0;
  int ng = (n + 63) >> 6;
  for (int g = 0; g < ng; ++g) {
    int base = g << 6;
    dsh[lane] = diag[base + lane];        // one word per lane -> LDS
    u64 s = rem[g];                       // broadcast LDS read
    int valid = n - base;
    if (valid < 64) s |= (~0ull) << valid;  // nonexistent boxes = suppressed
    u64 kw = 0;
    #pragma unroll 1
    for (int c = 0; c < 8; ++c) {
      int b0 = c << 3;
      u64 e0 = dsh[b0 + 0], e1 = dsh[b0 + 1], e2 = dsh[b0 + 2], e3 = dsh[b0 + 3];
      u64 e4 = dsh[b0 + 4], e5 = dsh[b0 + 5], e6 = dsh[b0 + 6], e7 = dsh[b0 + 7];
      #define STEP(Q, EQ) if (!((s >> (b0 + Q)) & 1ull)) { kw |= 1ull << (b0 + Q); s |= EQ; }
      STEP(0, e0) STEP(1, e1) STEP(2, e2) STEP(3, e3)
      STEP(4, e4) STEP(5, e5) STEP(6, e6) STEP(7, e7)
      #undef STEP
    }
    int k = base + lane;
    if (k < n) keep[sidx[k]] = ((kw >> lane) & 1ull) ? 1.0f : 0.0f;
    // fold kept rows into future-group suppression state (lane-parallel)
    u64 a0 = 0, a1 = 0, a2 = 0;
    u64 kk = kw;
    while (kk) {
      int b = __ffsll((long long)kk) - 1;
      kk &= kk - 1;
      const u64* row = mask + (size_t)(base + b) * wstride;
      a0 |= row[lane];
      if (lane + 64 < ng) a1 |= row[lane + 64];
      if (lane + 128 < ng) a2 |= row[lane + 128];
    }
    rem[lane] |= a0;
    rem[lane + 64] |= a1;
    rem[lane + 128] |= a2;
  }
}

__global__ __launch_bounds__(64, 1) void k_scan2(const u64* __restrict__ mask,
                                                 const u64* __restrict__ diag,
                                                 const int* __restrict__ sidx,
                                                 float* __restrict__ keep,
                                                 int n, int wstride) {
  __shared__ u64 rem[192];
  __shared__ u64 dsh[64];
  scan_body(mask, diag, sidx, keep, n, wstride, rem, dsh);
}

// Pairwise IoU, original order, WITH clamp. Loose 2e-2 threshold -> fast rcp.
__device__ __forceinline__ float iou_one(float li, float ti, float ri, float bi, float ai,
                                         float lj, float tj, float rj, float bj, float aj) {
  float lmax = fmaxf(li, lj);
  float tmax = fmaxf(ti, tj);
  float rmin = fminf(ri, rj);
  float bmin = fminf(bi, bj);
  float w = fmaxf(rmin - lmax, 0.0f);
  float h = fmaxf(bmin - tmax, 0.0f);
  float inter = w * h;
  float denom = (ai + aj) - inter;
  return inter * __builtin_amdgcn_rcpf(denom);
}

__device__ __forceinline__ void iou_body(const float4* __restrict__ boxes,
                                         float* __restrict__ out,
                                         int n, int rpb, int bx, int by) {
  int nj4 = (n + 3) >> 2;
  int j4 = bx * 256 + threadIdx.x;
  if (j4 >= nj4) return;
  int j = j4 << 2;
  int jc1 = min(j + 1, n - 1), jc2 = min(j + 2, n - 1), jc3 = min(j + 3, n - 1);
  float l0,t0,r0,b0,a0, l1,t1,r1,b1,a1, l2,t2,r2,b2,a2, l3,t3,r3,b3,a3;
  conv_box(boxes[j],   l0,t0,r0,b0,a0);
  conv_box(boxes[jc1], l1,t1,r1,b1,a1);
  conv_box(boxes[jc2], l2,t2,r2,b2,a2);
  conv_box(boxes[jc3], l3,t3,r3,b3,a3);
  bool full = (j + 3) < n;
  for (int rr = 0; rr < rpb; ++rr) {
    int i = by * rpb + rr;
    if (i >= n) return;
    float li,ti,ri,bi,ai;
    conv_box(boxes[i], li,ti,ri,bi,ai);
    float4 o;
    o.x = iou_one(li,ti,ri,bi,ai, l0,t0,r0,b0,a0);
    o.y = iou_one(li,ti,ri,bi,ai, l1,t1,r1,b1,a1);
    o.z = iou_one(li,ti,ri,bi,ai, l2,t2,r2,b2,a2);
    o.w = iou_one(li,ti,ri,bi,ai, l3,t3,r3,b3,a3);
    size_t row = (size_t)i * n;
    if (full) {
      *reinterpret_cast<float4*>(out + row + j) = o;
    } else {
      out[row + j] = o.x;
      if (j + 1 < n) out[row + j + 1] = o.y;
      if (j + 2 < n) out[row + j + 2] = o.z;
    }
  }
}

__global__ void k_iou(const float4* __restrict__ boxes, float* __restrict__ out,
                      int n, int rpb) {
  iou_body(boxes, out, n, rpb, blockIdx.x, blockIdx.y);
}

// Fused: block 0 (wave 0 only) runs the serial NMS scan from d_ws while all
// other blocks stream the 400MB IoU matrix — scan latency hides under the
// write-bound IoU. No hazard: scan reads ws + writes keep; iou writes out[0,NN).
__global__ __launch_bounds__(256) void k_fused(const float4* __restrict__ boxes,
                                               float* __restrict__ out,
                                               const u64* __restrict__ mask,
                                               const u64* __restrict__ diag,
                                               const int* __restrict__ sidx,
                                               float* __restrict__ keep,
                                               int n, int wstride, int rpb, int gx) {
  __shared__ u64 rem[192];
  __shared__ u64 dsh[64];
  if (blockIdx.x == 0) {
    if (threadIdx.x < 64)
      scan_body(mask, diag, sidx, keep, n, wstride, rem, dsh);
    return;
  }
  int id = blockIdx.x - 1;
  iou_body(boxes, out, n, rpb, id % gx, id / gx);
}

extern "C" void kernel_launch(void* const* d_in, const int* in_sizes, int n_in,
                              void* d_out, int out_size, void* d_ws, size_t ws_size,
                              hipStream_t stream) {
  const float* boxes = (const float*)d_in[0];
  const float* scores = (const float*)d_in[1];
  int n = in_sizes[1];
  float* out = (float*)d_out;
  size_t NN = (size_t)n * (size_t)n;
  float* keep = out + NN;

  int words = (n + 63) >> 6;
  int wstride = (words + 3) & ~3;
  size_t need = (size_t)n * wstride * 8          // mask
              + (size_t)words * 64 * 8           // diag
              + 256                              // align slack
              + (size_t)n * 4 * 7;               // sl,st,sr,sb,sa,sidx,rank
  bool use_ws = (ws_size >= need);

  char* base = use_ws ? (char*)d_ws : (char*)d_out;
  size_t off = 0;
  u64* mask = (u64*)(base + off); off += (size_t)n * wstride * 8;
  u64* diag = (u64*)(base + off); off += (size_t)words * 64 * 8;
  off = (off + 255) & ~(size_t)255;
  float* sl  = (float*)(base + off); off += (size_t)n * 4;
  float* st_ = (float*)(base + off); off += (size_t)n * 4;
  float* sr  = (float*)(base + off); off += (size_t)n * 4;
  float* sb  = (float*)(base + off); off += (size_t)n * 4;
  float* sa  = (float*)(base + off); off += (size_t)n * 4;
  int* sidx  = (int*)(base + off); off += (size_t)n * 4;
  int* rank  = (int*)(base + off); off += (size_t)n * 4;

  int nb = (n + 255) / 256;
  k_zero<<<nb, 256, 0, stream>>>(rank, n);

  int jblocks = 40;
  int jchunk = (n + jblocks - 1) / jblocks;
  k_rank<<<dim3(nb, jblocks), 256, 0, stream>>>(scores, rank, n, jchunk);

  k_scatter<<<nb, 256, 0, stream>>>((const float4*)boxes, rank, sl, st_, sr, sb, sa, sidx, n);

  k_mask<<<dim3(nb, words), 256, 0, stream>>>(sl, st_, sr, sb, sa, mask, diag, n, wstride);

  int rpb = 10;
  int nj4 = (n + 3) >> 2;
  int gx = (nj4 + 255) / 256;
  int gy = (n + rpb - 1) / rpb;

  if (use_ws) {
    k_fused<<<gx * gy + 1, 256, 0, stream>>>((const float4*)boxes, out, mask, diag,
                                             sidx, keep, n, wstride, rpb, gx);
  } else {
    // scratch lives in front of out: must finish scan before iou overwrites it
    k_scan2<<<1, 64, 0, stream>>>(mask, diag, sidx, keep, n, wstride);
    k_iou<<<dim3(gx, gy), 256, 0, stream>>>((const float4*)boxes, out, n, rpb);
  }
}